// Round 8
// baseline (114.611 us; speedup 1.0000x reference)
//
#include <hip/hip_runtime.h>
#include <hip/hip_bf16.h>
#include <math.h>

// SimCLR NT-Xent: B=4096, D=256, n=8192, T=0.5.
// z' = sqrt(K1) * rownorm(concat(a,b)) as bf16, row-swizzled:
//   stored_byte_in_row = logical_byte ^ ((row&7)<<4)
// MFMA(z', z'^T) = K1 * dot (K1 = 2*log2 e) -> exp(sim) = exp2(MFMA out).
// Round 8: T15 epilogue-deferral — two accumulator sets (cA/cB by phase
// parity); flush (exp2+accum) of the PREVIOUS phase's set is issued after
// the current phase's MFMA block, so trans/VALU work overlaps the matrix
// pipe instead of serially stalling the in-order wave on the last MFMA.
// Priming: cB = -1e30 so its first flush adds exp2(-1e30) = 0 (branch-free).
// loss = mean( ln2 * (log2(S_i - exp2(self_i)) - K1*posdot_i) ).

#define NROWS 8192
#define BHALF 4096
#define DDIM  256
#define ROWB  512                 // bytes per bf16 row
#define JSPLIT 16
#define JCHUNK (NROWS / JSPLIT)   // 512 cols per block
#define JT 64                     // cols per pipeline step
#define NSTEPS (JCHUNK / JT)      // 8
#define TILEB (JT * ROWB)         // 32 KiB per LDS buffer

#define SQRT_K1 1.6986436f        // sqrt(2*log2(e))
#define LN2F 0.6931471805599453f

typedef __attribute__((ext_vector_type(8))) __bf16 bf16x8;
typedef __attribute__((ext_vector_type(4))) float f32x4;

#if __has_builtin(__builtin_amdgcn_exp2f)
#define FEXP2(x) __builtin_amdgcn_exp2f(x)
#else
#define FEXP2(x) __exp2f(x)
#endif
#if __has_builtin(__builtin_amdgcn_logf)
#define FLOG2(x) __builtin_amdgcn_logf(x)
#else
#define FLOG2(x) __log2f(x)
#endif

__device__ __forceinline__ float bfu(unsigned short u) {
  union { unsigned v; float f; } x; x.v = ((unsigned)u) << 16; return x.f;
}

// ---------------- Kernel 1: normalize+scale rows -> swizzled bf16 ----------
__global__ __launch_bounds__(256) void norm_kernel(
    const float* __restrict__ a, const float* __restrict__ b,
    char* __restrict__ zb, float* __restrict__ selfdot) {
  int row = blockIdx.x * 4 + (threadIdx.x >> 6);
  int lane = threadIdx.x & 63;
  const float* src = (row < BHALF) ? (a + (size_t)row * DDIM)
                                   : (b + (size_t)(row - BHALF) * DDIM);
  float4 v = ((const float4*)src)[lane];
  float ss = v.x * v.x + v.y * v.y + v.z * v.z + v.w * v.w;
  #pragma unroll
  for (int m = 1; m < 64; m <<= 1) ss += __shfl_xor(ss, m, 64);
  float inv = rsqrtf(ss);
  inv = inv * (1.5f - 0.5f * ss * inv * inv);
  float sc = inv * SQRT_K1;   // bake sqrt(K1) into both operands

  union { __hip_bfloat16 h; unsigned short u; } c0, c1, c2, c3;
  c0.h = __float2bfloat16(v.x * sc);
  c1.h = __float2bfloat16(v.y * sc);
  c2.h = __float2bfloat16(v.z * sc);
  c3.h = __float2bfloat16(v.w * sc);
  // scaled self-dot of the bf16-rounded row (= what MFMA produces on diag)
  float q0 = bfu(c0.u), q1 = bfu(c1.u), q2 = bfu(c2.u), q3 = bfu(c3.u);
  float sq = q0 * q0 + q1 * q1 + q2 * q2 + q3 * q3;
  #pragma unroll
  for (int m = 1; m < 64; m <<= 1) sq += __shfl_xor(sq, m, 64);

  ushort4 o = make_ushort4(c0.u, c1.u, c2.u, c3.u);
  int off = row * ROWB + ((lane * 8) ^ ((row & 7) << 4));
  *(ushort4*)(zb + off) = o;
  if (lane == 0) selfdot[row] = sq;
}

// ---------------- Kernel 2: z z^T + exp2 row-sums, deferred epilogue -------
// Grid (32, 16): rb = x (256 rows), js = y (512 cols). 4 waves x 64 rows.
// A resident in VGPRs (full K=256). B: 8 steps of 64 cols, double-buffered
// LDS via global_load_lds, counted vmcnt, T15 two-set accumulator pipeline.
__global__ __launch_bounds__(256, 2) void sim_kernel(
    const char* __restrict__ zb, float* __restrict__ s_part) {
  __shared__ __align__(16) char lds[2 * TILEB];  // 64 KiB
  int wave = threadIdx.x >> 6;
  int lane = threadIdx.x & 63;
  int lrow = lane & 15;
  int kgrp = lane >> 4;
  int sw = (lrow & 7) << 4;
  int r0 = blockIdx.x * 256 + wave * 64;
  int jbase = blockIdx.y * JCHUNK;

  int koff[8];
  #pragma unroll
  for (int kk = 0; kk < 8; ++kk) koff[kk] = (kk * 64 + kgrp * 16) ^ sw;

  // --- preload A fragments (64 rows x K=256), scaled z ---
  bf16x8 af[4][8];
  #pragma unroll
  for (int rf = 0; rf < 4; ++rf) {
    const char* rp = zb + (size_t)(r0 + rf * 16 + lrow) * ROWB;
    #pragma unroll
    for (int kk = 0; kk < 8; ++kk)
      af[rf][kk] = *(const bf16x8*)(rp + koff[kk]);
  }

  float sacc[4][4] = {};

  // two accumulator sets (phase parity); prime B so first flush adds 0
  f32x4 cA0, cA1, cA2, cA3, cB0, cB1, cB2, cB3;
  cB0 = cB1 = cB2 = cB3 = (f32x4){-1e30f, -1e30f, -1e30f, -1e30f};

  #define MFMA_BLK(d0, d1, d2, d3, lbr) do {                                  \
    bf16x8 bf[8];                                                             \
    _Pragma("unroll")                                                         \
    for (int kk = 0; kk < 8; ++kk)                                            \
      bf[kk] = *(const bf16x8*)((lbr) + koff[kk]);                            \
    d0 = (f32x4){0.f, 0.f, 0.f, 0.f};                                         \
    d1 = (f32x4){0.f, 0.f, 0.f, 0.f};                                         \
    d2 = (f32x4){0.f, 0.f, 0.f, 0.f};                                         \
    d3 = (f32x4){0.f, 0.f, 0.f, 0.f};                                         \
    __builtin_amdgcn_s_setprio(1);                                            \
    _Pragma("unroll")                                                         \
    for (int kk = 0; kk < 8; ++kk) {                                          \
      d0 = __builtin_amdgcn_mfma_f32_16x16x32_bf16(af[0][kk], bf[kk], d0, 0, 0, 0); \
      d1 = __builtin_amdgcn_mfma_f32_16x16x32_bf16(af[1][kk], bf[kk], d1, 0, 0, 0); \
      d2 = __builtin_amdgcn_mfma_f32_16x16x32_bf16(af[2][kk], bf[kk], d2, 0, 0, 0); \
      d3 = __builtin_amdgcn_mfma_f32_16x16x32_bf16(af[3][kk], bf[kk], d3, 0, 0, 0); \
    }                                                                         \
    __builtin_amdgcn_s_setprio(0);                                            \
  } while (0)

  #define FLUSH(d0, d1, d2, d3) do {                                          \
    _Pragma("unroll")                                                         \
    for (int r = 0; r < 4; ++r) {                                             \
      sacc[0][r] += FEXP2(d0[r]);                                             \
      sacc[1][r] += FEXP2(d1[r]);                                             \
      sacc[2][r] += FEXP2(d2[r]);                                             \
      sacc[3][r] += FEXP2(d3[r]);                                             \
    }                                                                         \
  } while (0)

  // staging: linear 32KB tile copy (z pre-swizzled in global), 8KB per wave
  #define STAGE(buf, j0) do {                                                 \
    const char* g_ = zb + (size_t)(j0) * ROWB + wave * 8192 + lane * 16;      \
    char* l_ = lds + (buf) * TILEB + wave * 8192;                             \
    _Pragma("unroll")                                                         \
    for (int c8 = 0; c8 < 8; ++c8)                                            \
      __builtin_amdgcn_global_load_lds(                                       \
          (const __attribute__((address_space(1))) void*)(g_ + c8 * 1024),    \
          (__attribute__((address_space(3))) void*)(l_ + c8 * 1024),          \
          16, 0, 0);                                                          \
  } while (0)

  // prologue: 2-deep prefetch; vmcnt(8) certifies tile 0 (tile 1 in flight)
  STAGE(0, jbase);
  STAGE(1, jbase + JT);
  asm volatile("s_waitcnt vmcnt(8)" ::: "memory");
  __builtin_amdgcn_sched_barrier(0);
  __builtin_amdgcn_s_barrier();

  for (int s = 0; s < NSTEPS; ++s) {
    const char* lb = lds + (s & 1) * TILEB;
    // phase 0 (even): compute A, flush B (prev phase 3, or primed zero)
    MFMA_BLK(cA0, cA1, cA2, cA3, lb + 0 * 8192 + lrow * ROWB);
    FLUSH(cB0, cB1, cB2, cB3);
    // phase 1 (odd): compute B, flush A
    MFMA_BLK(cB0, cB1, cB2, cB3, lb + 1 * 8192 + lrow * ROWB);
    FLUSH(cA0, cA1, cA2, cA3);
    // phase 2
    MFMA_BLK(cA0, cA1, cA2, cA3, lb + 2 * 8192 + lrow * ROWB);
    FLUSH(cB0, cB1, cB2, cB3);
    // phase 3
    MFMA_BLK(cB0, cB1, cB2, cB3, lb + 3 * 8192 + lrow * ROWB);
    FLUSH(cA0, cA1, cA2, cA3);

    if (s + 1 < NSTEPS) {
      __builtin_amdgcn_s_barrier();   // all waves done reading buf[s&1]
      if (s + 2 < NSTEPS) {
        STAGE(s & 1, jbase + (s + 2) * JT);
        asm volatile("s_waitcnt vmcnt(8)" ::: "memory");  // tile s+1 ready
      } else {
        asm volatile("s_waitcnt vmcnt(0)" ::: "memory");
      }
      __builtin_amdgcn_sched_barrier(0);
      __builtin_amdgcn_s_barrier();
    }
  }
  // drain the last pending set (phase 31 parity: B computed last)
  FLUSH(cB0, cB1, cB2, cB3);

  #undef STAGE
  #undef FLUSH
  #undef MFMA_BLK

  // reduce across the 16 column-lanes (C layout: col=lane&15, row=kgrp*4+r)
  #pragma unroll
  for (int rf = 0; rf < 4; ++rf) {
    #pragma unroll
    for (int r = 0; r < 4; ++r) {
      float v = sacc[rf][r];
      #pragma unroll
      for (int m = 1; m < 16; m <<= 1) v += __shfl_xor(v, m, 64);
      if (lrow == 0) {
        int grow = r0 + rf * 16 + kgrp * 4 + r;
        s_part[(size_t)grow * JSPLIT + blockIdx.y] = v;
      }
    }
  }
}

// ---------------- Kernel 3: per-row term (pos dot + assemble) --------------
// 512 blocks x 4 waves x 4 rows.
__global__ __launch_bounds__(256) void rowterm_kernel(
    const char* __restrict__ zb, const float* __restrict__ s_part,
    const float* __restrict__ selfdot, float* __restrict__ bpart) {
  int wave = threadIdx.x >> 6;
  int lane = threadIdx.x & 63;
  int rbase = blockIdx.x * 16 + wave * 4;
  float wacc = 0.f;
  #pragma unroll
  for (int rr = 0; rr < 4; ++rr) {
    int i = rbase + rr;
    int j = i ^ BHALF;                       // (i+B) mod 2B
    int wo = (lane * 8) ^ ((i & 7) << 4);    // j&7 == i&7 (4096 % 8 == 0)
    ushort4 zi = *(const ushort4*)(zb + (size_t)i * ROWB + wo);
    ushort4 zj = *(const ushort4*)(zb + (size_t)j * ROWB + wo);
    float dot = bfu(zi.x) * bfu(zj.x) + bfu(zi.y) * bfu(zj.y) +
                bfu(zi.z) * bfu(zj.z) + bfu(zi.w) * bfu(zj.w);
    float sp = (lane < JSPLIT) ? s_part[(size_t)i * JSPLIT + lane] : 0.f;
    #pragma unroll
    for (int m = 1; m < 64; m <<= 1) {
      dot += __shfl_xor(dot, m, 64);
      sp += __shfl_xor(sp, m, 64);
    }
    float S = sp - FEXP2(selfdot[i]);          // remove diagonal
    wacc += LN2F * (FLOG2(S) - dot);           // denom - pos (2's cancel)
  }
  __shared__ float red[4];
  if (lane == 0) red[wave] = wacc;
  __syncthreads();
  if (threadIdx.x == 0)
    bpart[blockIdx.x] = red[0] + red[1] + red[2] + red[3];
}

// ---------------- Kernel 4: final sum --------------------------------------
__global__ __launch_bounds__(512) void final_kernel(
    const float* __restrict__ bpart, float* __restrict__ out) {
  int t = threadIdx.x;  // 512 threads = 8 waves
  float v = bpart[t];
  #pragma unroll
  for (int m = 1; m < 64; m <<= 1) v += __shfl_xor(v, m, 64);
  __shared__ float r2[8];
  if ((t & 63) == 0) r2[t >> 6] = v;
  __syncthreads();
  if (t == 0) {
    float s = 0.f;
    #pragma unroll
    for (int w = 0; w < 8; ++w) s += r2[w];
    out[0] = s / (float)NROWS;
  }
}

// ---------------- Launcher --------------------------------------------------
extern "C" void kernel_launch(void* const* d_in, const int* in_sizes, int n_in,
                              void* d_out, int out_size, void* d_ws, size_t ws_size,
                              hipStream_t stream) {
  const float* a = (const float*)d_in[0];
  const float* b = (const float*)d_in[1];
  float* out = (float*)d_out;
  char* ws = (char*)d_ws;

  char* zb = ws;                                            // 4 MiB
  float* selfdot = (float*)(ws + (size_t)NROWS * ROWB);     // 32 KiB
  float* s_part = selfdot + NROWS;                          // 512 KiB
  float* bpart = s_part + (size_t)NROWS * JSPLIT;           // 2 KiB

  hipLaunchKernelGGL(norm_kernel, dim3(NROWS / 4), dim3(256), 0, stream,
                     a, b, zb, selfdot);
  hipLaunchKernelGGL(sim_kernel, dim3(32, JSPLIT), dim3(256), 0, stream,
                     zb, s_part);
  hipLaunchKernelGGL(rowterm_kernel, dim3(512), dim3(256), 0, stream,
                     zb, s_part, selfdot, bpart);
  hipLaunchKernelGGL(final_kernel, dim3(1), dim3(512), 0, stream, bpart, out);
}

// Round 9
// 49.961 us; speedup vs baseline: 2.2940x; 2.2940x over previous
//
#include <hip/hip_runtime.h>
#include <hip/hip_bf16.h>
#include <math.h>

// SimCLR NT-Xent: B=4096, D=256, n=8192, T=0.5.
// z' = sqrt(K1) * rownorm(concat(a,b)) as bf16, row-swizzled:
//   stored_byte_in_row = logical_byte ^ ((row&7)<<4)
// MFMA(z', z'^T) = K1 * dot (K1 = 2*log2 e) -> exp(sim) = exp2(MFMA out).
// Round 9: m201-style fine-phase pipeline. 8 waves x 32 rows, 512 thr,
// 1 block/CU. Per 64-col tile: 4 phases of {ds_read || stage(t+2) ||
// exp2-flush(prev acc set) -> barrier -> MFMA cluster -> barrier}.
// Triple-buffered LDS, counted vmcnt(4) at tile boundary only (never 0
// in-loop). Two acc sets X/Y (static names, no spill: af=64 VGPR only).
// Grid (js=8, rb=32): blockid%8 == js -> each XCD owns one B panel (L2).
// loss = mean( ln2 * (log2(S_i - exp2(self_i)) - K1*posdot_i) ).

#define NROWS 8192
#define BHALF 4096
#define DDIM  256
#define ROWB  512                 // bytes per bf16 row
#define JSPLIT 8
#define JCHUNK (NROWS / JSPLIT)   // 1024 cols per block
#define JT 64                     // cols per tile
#define NTILES (JCHUNK / JT)      // 16
#define TILEB (JT * ROWB)         // 32 KiB per LDS buffer

#define SQRT_K1 1.6986436f        // sqrt(2*log2(e))
#define LN2F 0.6931471805599453f

typedef __attribute__((ext_vector_type(8))) __bf16 bf16x8;
typedef __attribute__((ext_vector_type(4))) float f32x4;

#if __has_builtin(__builtin_amdgcn_exp2f)
#define FEXP2(x) __builtin_amdgcn_exp2f(x)
#else
#define FEXP2(x) __exp2f(x)
#endif
#if __has_builtin(__builtin_amdgcn_logf)
#define FLOG2(x) __builtin_amdgcn_logf(x)
#else
#define FLOG2(x) __log2f(x)
#endif

__device__ __forceinline__ float bfu(unsigned short u) {
  union { unsigned v; float f; } x; x.v = ((unsigned)u) << 16; return x.f;
}

// ---------------- Kernel 1: normalize+scale rows -> swizzled bf16 ----------
__global__ __launch_bounds__(256) void norm_kernel(
    const float* __restrict__ a, const float* __restrict__ b,
    char* __restrict__ zb, float* __restrict__ selfdot) {
  int row = blockIdx.x * 4 + (threadIdx.x >> 6);
  int lane = threadIdx.x & 63;
  const float* src = (row < BHALF) ? (a + (size_t)row * DDIM)
                                   : (b + (size_t)(row - BHALF) * DDIM);
  float4 v = ((const float4*)src)[lane];
  float ss = v.x * v.x + v.y * v.y + v.z * v.z + v.w * v.w;
  #pragma unroll
  for (int m = 1; m < 64; m <<= 1) ss += __shfl_xor(ss, m, 64);
  float inv = rsqrtf(ss);
  inv = inv * (1.5f - 0.5f * ss * inv * inv);
  float sc = inv * SQRT_K1;   // bake sqrt(K1) into both operands

  union { __hip_bfloat16 h; unsigned short u; } c0, c1, c2, c3;
  c0.h = __float2bfloat16(v.x * sc);
  c1.h = __float2bfloat16(v.y * sc);
  c2.h = __float2bfloat16(v.z * sc);
  c3.h = __float2bfloat16(v.w * sc);
  // scaled self-dot of the bf16-rounded row (= what MFMA produces on diag)
  float q0 = bfu(c0.u), q1 = bfu(c1.u), q2 = bfu(c2.u), q3 = bfu(c3.u);
  float sq = q0 * q0 + q1 * q1 + q2 * q2 + q3 * q3;
  #pragma unroll
  for (int m = 1; m < 64; m <<= 1) sq += __shfl_xor(sq, m, 64);

  ushort4 o = make_ushort4(c0.u, c1.u, c2.u, c3.u);
  int off = row * ROWB + ((lane * 8) ^ ((row & 7) << 4));
  *(ushort4*)(zb + off) = o;
  if (lane == 0) selfdot[row] = sq;
}

// ---------------- Kernel 2: z z^T + exp2 row-sums, fine-phase pipeline -----
__global__ __launch_bounds__(512, 2) void sim_kernel(
    const char* __restrict__ zb, float* __restrict__ s_part) {
  __shared__ __align__(16) char lds[3 * TILEB];  // 96 KiB, triple buffer
  int js = blockIdx.x;            // 0..7  (blockid%8 -> XCD)
  int rb = blockIdx.y;            // 0..31
  int wave = threadIdx.x >> 6;    // 0..7
  int lane = threadIdx.x & 63;
  int lrow = lane & 15;
  int kgrp = lane >> 4;
  int sw = (lrow & 7) << 4;
  int r0 = rb * 256 + wave * 32;
  int jbase = js * JCHUNK;

  int koff[8];
  #pragma unroll
  for (int kk = 0; kk < 8; ++kk) koff[kk] = (kk * 64 + kgrp * 16) ^ sw;

  // --- preload A fragments (32 rows x K=256), scaled z: 64 VGPRs ---
  bf16x8 af[2][8];
  #pragma unroll
  for (int rf = 0; rf < 2; ++rf) {
    const char* rp = zb + (size_t)(r0 + rf * 16 + lrow) * ROWB;
    #pragma unroll
    for (int kk = 0; kk < 8; ++kk)
      af[rf][kk] = *(const bf16x8*)(rp + koff[kk]);
  }

  float sacc[2][4] = {};
  // two accumulator sets; Y primed so its first flush adds exp2(-1e30)=0
  f32x4 X0, X1, Y0, Y1;
  X0 = X1 = Y0 = Y1 = (f32x4){-1e30f, -1e30f, -1e30f, -1e30f};

  // stage one quarter (8KB) of a 64-col tile; LDS dest wave-uniform base
  #define STAGE1(dstbuf, j0, portion) do {                                    \
    const char* g_ = zb + (size_t)(j0) * ROWB + (portion) * 8192 +            \
                     wave * 1024 + lane * 16;                                 \
    char* l_ = lds + (dstbuf) * TILEB + (portion) * 8192 + wave * 1024;       \
    __builtin_amdgcn_global_load_lds(                                         \
        (const __attribute__((address_space(1))) void*)g_,                    \
        (__attribute__((address_space(3))) void*)l_, 16, 0, 0);               \
  } while (0)

  // one phase: ds_read(ct) || stage 1/4 of tile t+2 || flush PRV set,
  // then barrier -> MFMA(CUR set) -> [ct3: counted vmcnt] -> barrier
  #define PHASE(ct, C0, C1, P0, P1) do {                                      \
    const char* lbr = lds + buf * TILEB + (ct) * 8192 + lrow * ROWB;          \
    bf16x8 bfv[8];                                                            \
    _Pragma("unroll")                                                         \
    for (int kk = 0; kk < 8; ++kk)                                            \
      bfv[kk] = *(const bf16x8*)(lbr + koff[kk]);                             \
    if (t + 2 < NTILES) STAGE1(dst, jbase + (t + 2) * JT, ct);                \
    _Pragma("unroll")                                                         \
    for (int r = 0; r < 4; ++r) {                                             \
      sacc[0][r] += FEXP2(P0[r]);                                             \
      sacc[1][r] += FEXP2(P1[r]);                                             \
    }                                                                         \
    __builtin_amdgcn_sched_barrier(0);                                        \
    __builtin_amdgcn_s_barrier();                                             \
    C0 = (f32x4){0.f, 0.f, 0.f, 0.f};                                         \
    C1 = (f32x4){0.f, 0.f, 0.f, 0.f};                                         \
    __builtin_amdgcn_s_setprio(1);                                            \
    _Pragma("unroll")                                                         \
    for (int kk = 0; kk < 8; ++kk) {                                          \
      C0 = __builtin_amdgcn_mfma_f32_16x16x32_bf16(af[0][kk], bfv[kk], C0, 0, 0, 0); \
      C1 = __builtin_amdgcn_mfma_f32_16x16x32_bf16(af[1][kk], bfv[kk], C1, 0, 0, 0); \
    }                                                                         \
    __builtin_amdgcn_s_setprio(0);                                            \
    if ((ct) == 3) {                                                          \
      if (t + 2 < NTILES)                                                     \
        asm volatile("s_waitcnt vmcnt(4)" ::: "memory");                      \
      else if (t + 1 < NTILES)                                                \
        asm volatile("s_waitcnt vmcnt(0)" ::: "memory");                      \
      __builtin_amdgcn_sched_barrier(0);                                      \
    }                                                                         \
    __builtin_amdgcn_s_barrier();                                             \
  } while (0)

  // prologue: fully stage tiles 0 and 1; certify tile 0 (vmcnt(4))
  #pragma unroll
  for (int p = 0; p < 4; ++p) STAGE1(0, jbase, p);
  #pragma unroll
  for (int p = 0; p < 4; ++p) STAGE1(1, jbase + JT, p);
  asm volatile("s_waitcnt vmcnt(4)" ::: "memory");
  __builtin_amdgcn_sched_barrier(0);
  __builtin_amdgcn_s_barrier();

  int buf = 0;
  for (int t = 0; t < NTILES; ++t) {
    int dst = buf + 2; if (dst >= 3) dst -= 3;   // (t+2)%3
    PHASE(0, X0, X1, Y0, Y1);
    PHASE(1, Y0, Y1, X0, X1);
    PHASE(2, X0, X1, Y0, Y1);
    PHASE(3, Y0, Y1, X0, X1);
    ++buf; if (buf == 3) buf = 0;
  }
  // drain last pending set (ct3 computed Y)
  #pragma unroll
  for (int r = 0; r < 4; ++r) {
    sacc[0][r] += FEXP2(Y0[r]);
    sacc[1][r] += FEXP2(Y1[r]);
  }
  #undef PHASE
  #undef STAGE1

  // reduce across the 16 column-lanes (C layout: col=lane&15, row=kgrp*4+r)
  #pragma unroll
  for (int rf = 0; rf < 2; ++rf) {
    #pragma unroll
    for (int r = 0; r < 4; ++r) {
      float v = sacc[rf][r];
      #pragma unroll
      for (int m = 1; m < 16; m <<= 1) v += __shfl_xor(v, m, 64);
      if (lrow == 0) {
        int grow = r0 + rf * 16 + kgrp * 4 + r;
        s_part[(size_t)grow * JSPLIT + js] = v;
      }
    }
  }
}

// ---------------- Kernel 3: per-row term (pos dot + assemble) --------------
// 512 blocks x 4 waves x 4 rows.
__global__ __launch_bounds__(256) void rowterm_kernel(
    const char* __restrict__ zb, const float* __restrict__ s_part,
    const float* __restrict__ selfdot, float* __restrict__ bpart) {
  int wave = threadIdx.x >> 6;
  int lane = threadIdx.x & 63;
  int rbase = blockIdx.x * 16 + wave * 4;
  float wacc = 0.f;
  #pragma unroll
  for (int rr = 0; rr < 4; ++rr) {
    int i = rbase + rr;
    int j = i ^ BHALF;                       // (i+B) mod 2B
    int wo = (lane * 8) ^ ((i & 7) << 4);    // j&7 == i&7 (4096 % 8 == 0)
    ushort4 zi = *(const ushort4*)(zb + (size_t)i * ROWB + wo);
    ushort4 zj = *(const ushort4*)(zb + (size_t)j * ROWB + wo);
    float dot = bfu(zi.x) * bfu(zj.x) + bfu(zi.y) * bfu(zj.y) +
                bfu(zi.z) * bfu(zj.z) + bfu(zi.w) * bfu(zj.w);
    float sp = (lane < JSPLIT) ? s_part[(size_t)i * JSPLIT + lane] : 0.f;
    #pragma unroll
    for (int m = 1; m < 64; m <<= 1) {
      dot += __shfl_xor(dot, m, 64);
      sp += __shfl_xor(sp, m, 64);
    }
    float S = sp - FEXP2(selfdot[i]);          // remove diagonal
    wacc += LN2F * (FLOG2(S) - dot);           // denom - pos (2's cancel)
  }
  __shared__ float red[4];
  if (lane == 0) red[wave] = wacc;
  __syncthreads();
  if (threadIdx.x == 0)
    bpart[blockIdx.x] = red[0] + red[1] + red[2] + red[3];
}

// ---------------- Kernel 4: final sum --------------------------------------
__global__ __launch_bounds__(512) void final_kernel(
    const float* __restrict__ bpart, float* __restrict__ out) {
  int t = threadIdx.x;  // 512 threads = 8 waves
  float v = bpart[t];
  #pragma unroll
  for (int m = 1; m < 64; m <<= 1) v += __shfl_xor(v, m, 64);
  __shared__ float r2[8];
  if ((t & 63) == 0) r2[t >> 6] = v;
  __syncthreads();
  if (t == 0) {
    float s = 0.f;
    #pragma unroll
    for (int w = 0; w < 8; ++w) s += r2[w];
    out[0] = s / (float)NROWS;
  }
}

// ---------------- Launcher --------------------------------------------------
extern "C" void kernel_launch(void* const* d_in, const int* in_sizes, int n_in,
                              void* d_out, int out_size, void* d_ws, size_t ws_size,
                              hipStream_t stream) {
  const float* a = (const float*)d_in[0];
  const float* b = (const float*)d_in[1];
  float* out = (float*)d_out;
  char* ws = (char*)d_ws;

  char* zb = ws;                                            // 4 MiB
  float* selfdot = (float*)(ws + (size_t)NROWS * ROWB);     // 32 KiB
  float* s_part = selfdot + NROWS;                          // 256 KiB
  float* bpart = s_part + (size_t)NROWS * JSPLIT;           // 2 KiB

  hipLaunchKernelGGL(norm_kernel, dim3(NROWS / 4), dim3(256), 0, stream,
                     a, b, zb, selfdot);
  hipLaunchKernelGGL(sim_kernel, dim3(JSPLIT, 32), dim3(512), 0, stream,
                     zb, s_part);
  hipLaunchKernelGGL(rowterm_kernel, dim3(512), dim3(256), 0, stream,
                     zb, s_part, selfdot, bpart);
  hipLaunchKernelGGL(final_kernel, dim3(1), dim3(512), 0, stream, bpart, out);
}